// Round 2
// baseline (364.768 us; speedup 1.0000x reference)
//
#include <hip/hip_runtime.h>
#include <math.h>

#define B_     1024
#define T_     80
#define D_     512
#define C_     78      // VOCAB+1
#define PRED_  30
#define BLANK_ 77

#define ROWS_PB 128          // rows (b*T flat) per block
#define KHALF   256          // split-K: 2 halves of 256
#define KCHUNK  64           // k staged per chunk per half
#define NCHUNK  (KHALF / KCHUNK)
#define PSTR    84           // partials LDS stride (84*4=336 B, 16B-aligned)

// GEMM [81920,512]x[512,78] fp32 + bias + softmax + argmax, fused.
// Block: 256 threads = 128 rows x 2 k-halves. acc[78]/thread; B rows broadcast from LDS.
__global__ __launch_bounds__(256, 3) void gemm_softmax_argmax(
    const float* __restrict__ feat,   // [B*T, 512]
    const float* __restrict__ W,      // [512, 78]
    const float* __restrict__ bias,   // [78]
    float* __restrict__ probs,        // [B*T, 78]
    int* __restrict__ best)           // [B*T]
{
    __shared__ __align__(16) float smem[ROWS_PB * PSTR];   // 43008 B: Ws(2*64*80=10240f) | part(128*84f)
    __shared__ float bias_s[C_];

    float (*Ws)[KCHUNK][80] = (float (*)[KCHUNK][80])smem; // [2][64][80]
    float (*part)[PSTR]     = (float (*)[PSTR])smem;

    const int tid = threadIdx.x;
    const int g   = tid >> 7;          // k-half
    const int r   = tid & 127;         // row within block
    const long row = (long)blockIdx.x * ROWS_PB + r;

    if (tid < C_) bias_s[tid] = bias[tid];

    float acc[C_];
    #pragma unroll
    for (int c = 0; c < C_; ++c) acc[c] = 0.f;

    const float* Arow = feat + row * D_ + g * KHALF;

    for (int kc = 0; kc < NCHUNK; ++kc) {
        __syncthreads();               // protect LDS reuse across chunks
        // stage W rows [kc*64,+64) for half 0 and [256+kc*64,+64) for half 1
        for (int i = tid; i < 2 * KCHUNK * C_; i += 256) {
            int h  = i / (KCHUNK * C_);
            int j  = i - h * (KCHUNK * C_);
            int kk = j / C_;
            int c  = j - kk * C_;
            Ws[h][kk][c] = W[(h * KHALF + kc * KCHUNK + kk) * C_ + c];
        }
        __syncthreads();

        const float* Ap = Arow + kc * KCHUNK;
        #pragma unroll 2
        for (int k4 = 0; k4 < KCHUNK / 4; ++k4) {
            float4 av = *(const float4*)(Ap + k4 * 4);
            #pragma unroll
            for (int j = 0; j < 4; ++j) {
                float a = (j == 0) ? av.x : (j == 1) ? av.y : (j == 2) ? av.z : av.w;
                const float* Bk = Ws[g][k4 * 4 + j];   // broadcast: all lanes same addr
                #pragma unroll
                for (int cg = 0; cg < 19; ++cg) {
                    float4 b = *(const float4*)(Bk + cg * 4);
                    acc[cg*4+0] = fmaf(a, b.x, acc[cg*4+0]);
                    acc[cg*4+1] = fmaf(a, b.y, acc[cg*4+1]);
                    acc[cg*4+2] = fmaf(a, b.z, acc[cg*4+2]);
                    acc[cg*4+3] = fmaf(a, b.w, acc[cg*4+3]);
                }
                float2 bt = *(const float2*)(Bk + 76);
                acc[76] = fmaf(a, bt.x, acc[76]);
                acc[77] = fmaf(a, bt.y, acc[77]);
            }
        }
    }

    __syncthreads();
    if (g == 1) {                      // upper k-half writes partials
        #pragma unroll
        for (int cg = 0; cg < 19; ++cg) {
            float4 p = make_float4(acc[cg*4], acc[cg*4+1], acc[cg*4+2], acc[cg*4+3]);
            *(float4*)(&part[r][cg*4]) = p;
        }
        *(float2*)(&part[r][76]) = make_float2(acc[76], acc[77]);
    }
    __syncthreads();

    if (g == 0) {
        #pragma unroll
        for (int cg = 0; cg < 19; ++cg) {
            float4 p = *(const float4*)(&part[r][cg*4]);
            acc[cg*4+0] += p.x; acc[cg*4+1] += p.y;
            acc[cg*4+2] += p.z; acc[cg*4+3] += p.w;
        }
        float2 pt = *(const float2*)(&part[r][76]);
        acc[76] += pt.x; acc[77] += pt.y;

        // bias + argmax (strict > keeps first index, matches np.argmax)
        float m = -INFINITY; int mi = 0;
        #pragma unroll
        for (int c = 0; c < C_; ++c) {
            float v = acc[c] + bias_s[c];
            acc[c] = v;
            if (v > m) { m = v; mi = c; }
        }
        // softmax
        float s = 0.f;
        #pragma unroll
        for (int c = 0; c < C_; ++c) {
            float e = __expf(acc[c] - m);
            acc[c] = e;
            s += e;
        }
        float inv = 1.0f / s;
        float* op = probs + row * C_;              // row*312 B: 8B-aligned -> float2 stores
        #pragma unroll
        for (int cg = 0; cg < 39; ++cg)
            *(float2*)(op + cg * 2) = make_float2(acc[cg*2] * inv, acc[cg*2+1] * inv);
        best[row] = mi;
    }
}

// CTC greedy collapse: merge repeats, drop blanks, pad -1 (as fp32)
__global__ __launch_bounds__(256) void ctc_decode(const int* __restrict__ best,
                                                  float* __restrict__ lab) {
    int b = blockIdx.x * 256 + threadIdx.x;
    if (b >= B_) return;
    const int* bp = best + b * T_;
    float* op = lab + (size_t)b * PRED_;
    int prev = -1, pos = 0;
    for (int t = 0; t < T_; ++t) {
        int v = bp[t];
        if (v != BLANK_ && v != prev) {
            if (pos < PRED_) op[pos] = (float)v;
            ++pos;
        }
        prev = v;
    }
    for (int i = (pos < PRED_ ? pos : PRED_); i < PRED_; ++i) op[i] = -1.0f;
}

extern "C" void kernel_launch(void* const* d_in, const int* in_sizes, int n_in,
                              void* d_out, int out_size, void* d_ws, size_t ws_size,
                              hipStream_t stream) {
    const float* feat = (const float*)d_in[0];   // fp32 [1024,80,512]
    const float* W    = (const float*)d_in[1];   // fp32 [512,78]
    const float* bias = (const float*)d_in[2];   // fp32 [78]
    // d_in[3]=y, d_in[4]=times : unused
    float* probs = (float*)d_out;
    float* lab   = probs + (size_t)B_ * T_ * C_;
    int*   best  = (int*)d_ws;                   // 81920 ints = 320 KB scratch

    hipLaunchKernelGGL(gemm_softmax_argmax, dim3((B_ * T_) / ROWS_PB), dim3(256), 0, stream,
                       feat, W, bias, probs, best);
    hipLaunchKernelGGL(ctc_decode, dim3(4), dim3(256), 0, stream, best, lab);
}

// Round 3
// 269.099 us; speedup vs baseline: 1.3555x; 1.3555x over previous
//
#include <hip/hip_runtime.h>
#include <math.h>

#define B_     1024
#define T_     80
#define D_     512
#define C_     78      // VOCAB+1
#define PRED_  30
#define BLANK_ 77
#define NKK    16      // 512 / 32
#define FRAG   512     // ushorts per fragment block (64 lanes * 8 halves)
#define PLANE_STRIDE (5 * NKK * FRAG)   // 40960 ushorts per plane

typedef __attribute__((ext_vector_type(8))) _Float16 f16x8;
typedef __attribute__((ext_vector_type(4))) float    f32x4;

// Split W [512,78] fp32 into two f16 planes (w1 = rnd(w), w2 = rnd(w - w1)),
// stored fragment-linear: [plane][ct][kk][lane][j], so the main loop's B load
// is base + lane*16B (perfectly coalesced, L2-resident).
__global__ __launch_bounds__(256) void prep_w(const float* __restrict__ W,
                                              ushort* __restrict__ Wf) {
    int i = blockIdx.x * 256 + threadIdx.x;
    if (i >= 2 * PLANE_STRIDE) return;
    int j    = i & 7;
    int lane = (i >> 3) & 63;
    int kk   = (i >> 9) & 15;
    int rest = i >> 13;          // plane*5 + ct
    int ct   = rest % 5;
    int plane = rest / 5;
    int q = lane >> 4, n = lane & 15;
    int k = kk * 32 + q * 8 + j;
    int c = ct * 16 + n;
    float v = (c < C_) ? W[k * C_ + c] : 0.f;
    _Float16 h1 = (_Float16)v;
    union { _Float16 h; ushort u; } cv;
    cv.h = (plane == 0) ? h1 : (_Float16)(v - (float)h1);
    Wf[i] = cv.u;
}

// Block = 320 threads (5 waves) = 2 batch elements (160 rows).
// Wave w: rows w*16..w*16+15 of both batch elements, all 80 (padded) cols.
// A frag: lane holds A[m=lane&15][k=(lane>>4)*8+j] -> 32B contiguous fp32, split in-reg.
// B frag: fragment-linear Wf load at lane*8 ushorts.
// C/D: col = lane&15, row = (lane>>4)*4 + reg  (m89-verified layout).
__global__ __launch_bounds__(320, 2) void gemm_ctc(
    const float* __restrict__ feat,   // [81920, 512] fp32
    const ushort* __restrict__ Wf,    // fragment-linear f16 split planes
    const float* __restrict__ bias,   // [78] fp32
    float* __restrict__ probs,        // [81920, 78] fp32
    float* __restrict__ lab)          // [1024, 30] fp32
{
    __shared__ int best_s[2][T_];

    const int tid  = threadIdx.x;
    const int w    = tid >> 6;
    const int lane = tid & 63;
    const int q    = lane >> 4;
    const int n    = lane & 15;

    f32x4 acc[2][5];
    #pragma unroll
    for (int t = 0; t < 2; ++t)
        #pragma unroll
        for (int ct = 0; ct < 5; ++ct)
            acc[t][ct] = (f32x4){0.f, 0.f, 0.f, 0.f};

    const size_t row0 = (size_t)blockIdx.x * 160 + w * 16 + n;
    const float*  a0p = feat + row0 * D_ + q * 8;
    const float*  a1p = a0p + (size_t)80 * D_;
    const ushort* bp0 = Wf + lane * 8;

    #pragma unroll 2
    for (int kk = 0; kk < NKK; ++kk) {
        float4 lo0 = *(const float4*)(a0p + kk * 32);
        float4 hi0 = *(const float4*)(a0p + kk * 32 + 4);
        float4 lo1 = *(const float4*)(a1p + kk * 32);
        float4 hi1 = *(const float4*)(a1p + kk * 32 + 4);
        float v0[8] = {lo0.x, lo0.y, lo0.z, lo0.w, hi0.x, hi0.y, hi0.z, hi0.w};
        float v1[8] = {lo1.x, lo1.y, lo1.z, lo1.w, hi1.x, hi1.y, hi1.z, hi1.w};
        f16x8 a01, a02, a11, a12;
        #pragma unroll
        for (int j = 0; j < 8; ++j) {
            _Float16 h = (_Float16)v0[j];
            a01[j] = h;
            a02[j] = (_Float16)(v0[j] - (float)h);
            _Float16 g = (_Float16)v1[j];
            a11[j] = g;
            a12[j] = (_Float16)(v1[j] - (float)g);
        }
        #pragma unroll
        for (int ct = 0; ct < 5; ++ct) {
            const ushort* bp = bp0 + (ct * NKK + kk) * FRAG;
            f16x8 b1 = *(const f16x8*)bp;
            f16x8 b2 = *(const f16x8*)(bp + PLANE_STRIDE);
            acc[0][ct] = __builtin_amdgcn_mfma_f32_16x16x32_f16(a01, b1, acc[0][ct], 0, 0, 0);
            acc[0][ct] = __builtin_amdgcn_mfma_f32_16x16x32_f16(a02, b1, acc[0][ct], 0, 0, 0);
            acc[0][ct] = __builtin_amdgcn_mfma_f32_16x16x32_f16(a01, b2, acc[0][ct], 0, 0, 0);
            acc[0][ct] = __builtin_amdgcn_mfma_f32_16x16x32_f16(a02, b2, acc[0][ct], 0, 0, 0);
            acc[1][ct] = __builtin_amdgcn_mfma_f32_16x16x32_f16(a11, b1, acc[1][ct], 0, 0, 0);
            acc[1][ct] = __builtin_amdgcn_mfma_f32_16x16x32_f16(a12, b1, acc[1][ct], 0, 0, 0);
            acc[1][ct] = __builtin_amdgcn_mfma_f32_16x16x32_f16(a11, b2, acc[1][ct], 0, 0, 0);
            acc[1][ct] = __builtin_amdgcn_mfma_f32_16x16x32_f16(a12, b2, acc[1][ct], 0, 0, 0);
        }
    }

    // ---- epilogue: bias + argmax + softmax + direct stores ----
    #pragma unroll
    for (int t = 0; t < 2; ++t) {
        float x[5][4];
        #pragma unroll
        for (int ct = 0; ct < 5; ++ct) {
            int c = ct * 16 + n;
            bool valid = (c < C_);
            float bv = valid ? bias[c] : 0.f;
            #pragma unroll
            for (int r = 0; r < 4; ++r)
                x[ct][r] = valid ? (acc[t][ct][r] + bv) : -INFINITY;
        }
        float av[4]; int ai[4];
        #pragma unroll
        for (int r = 0; r < 4; ++r) {
            av[r] = x[0][r]; ai[r] = n;
            #pragma unroll
            for (int ct = 1; ct < 5; ++ct) {
                int c = ct * 16 + n;
                if (x[ct][r] > av[r]) { av[r] = x[ct][r]; ai[r] = c; }
            }
        }
        #pragma unroll
        for (int off = 8; off >= 1; off >>= 1) {
            #pragma unroll
            for (int r = 0; r < 4; ++r) {
                float ov = __shfl_xor(av[r], off, 16);
                int   oi = __shfl_xor(ai[r], off, 16);
                if (ov > av[r] || (ov == av[r] && oi < ai[r])) { av[r] = ov; ai[r] = oi; }
            }
        }
        float s[4] = {0.f, 0.f, 0.f, 0.f};
        #pragma unroll
        for (int ct = 0; ct < 5; ++ct)
            #pragma unroll
            for (int r = 0; r < 4; ++r) {
                x[ct][r] = __expf(x[ct][r] - av[r]);   // -INF -> 0
                s[r] += x[ct][r];
            }
        #pragma unroll
        for (int off = 8; off >= 1; off >>= 1)
            #pragma unroll
            for (int r = 0; r < 4; ++r) s[r] += __shfl_xor(s[r], off, 16);

        const size_t growb = (size_t)blockIdx.x * 160 + t * 80 + w * 16 + q * 4;
        #pragma unroll
        for (int r = 0; r < 4; ++r) {
            float inv = 1.f / s[r];
            float* op = probs + (growb + r) * C_;
            #pragma unroll
            for (int ct = 0; ct < 5; ++ct) {
                int c = ct * 16 + n;
                if (c < C_) op[c] = x[ct][r] * inv;
            }
        }
        if (n == 0) {
            #pragma unroll
            for (int r = 0; r < 4; ++r) best_s[t][w * 16 + q * 4 + r] = ai[r];
        }
    }
    __syncthreads();

    // in-block CTC greedy decode (2 batch elements)
    if (tid < 2) {
        const int* bs = best_s[tid];
        float* op = lab + ((size_t)blockIdx.x * 2 + tid) * PRED_;
        int prev = -1, pos = 0;
        for (int t2 = 0; t2 < T_; ++t2) {
            int v = bs[t2];
            if (v != BLANK_ && v != prev) {
                if (pos < PRED_) op[pos] = (float)v;
                ++pos;
            }
            prev = v;
        }
        for (int i2 = (pos < PRED_ ? pos : PRED_); i2 < PRED_; ++i2) op[i2] = -1.f;
    }
}

extern "C" void kernel_launch(void* const* d_in, const int* in_sizes, int n_in,
                              void* d_out, int out_size, void* d_ws, size_t ws_size,
                              hipStream_t stream) {
    const float* feat = (const float*)d_in[0];   // fp32 [1024,80,512]
    const float* W    = (const float*)d_in[1];   // fp32 [512,78]
    const float* bias = (const float*)d_in[2];   // fp32 [78]
    // d_in[3]=y, d_in[4]=times : unused
    float*  probs = (float*)d_out;
    float*  lab   = probs + (size_t)B_ * T_ * C_;
    ushort* Wf    = (ushort*)d_ws;               // 163840 B scratch

    hipLaunchKernelGGL(prep_w, dim3(320), dim3(256), 0, stream, W, Wf);
    hipLaunchKernelGGL(gemm_ctc, dim3(512), dim3(320), 0, stream,
                       feat, Wf, bias, probs, lab);
}

// Round 4
// 265.136 us; speedup vs baseline: 1.3758x; 1.0149x over previous
//
#include <hip/hip_runtime.h>
#include <math.h>

#define B_     1024
#define T_     80
#define D_     512
#define C_     78      // VOCAB+1
#define PRED_  30
#define BLANK_ 77
#define NKK    16      // 512 / 32
#define FRAG   512     // ushorts per fragment block (64 lanes * 8 halves)
#define PLANE_STRIDE (5 * NKK * FRAG)   // 40960 ushorts per plane
#define ROWS_PB 160    // rows per block (2 batch elements)

typedef __attribute__((ext_vector_type(8))) _Float16 f16x8;
typedef __attribute__((ext_vector_type(4))) float    f32x4;

__device__ __forceinline__ void load_lds16(const void* g, void* l) {
    __builtin_amdgcn_global_load_lds(
        (const __attribute__((address_space(1))) unsigned int*)g,
        (__attribute__((address_space(3))) unsigned int*)l, 16, 0, 0);
}

// Split W [512,78] fp32 into two f16 planes (w1 = rnd(w), w2 = rnd(w - w1)),
// fragment-linear: [plane][ct][kk][lane][j] -> main-loop B load = base + lane*16B.
__global__ __launch_bounds__(256) void prep_w(const float* __restrict__ W,
                                              ushort* __restrict__ Wf) {
    int i = blockIdx.x * 256 + threadIdx.x;
    if (i >= 2 * PLANE_STRIDE) return;
    int j    = i & 7;
    int lane = (i >> 3) & 63;
    int kk   = (i >> 9) & 15;
    int rest = i >> 13;          // plane*5 + ct
    int ct   = rest % 5;
    int plane = rest / 5;
    int q = lane >> 4, n = lane & 15;
    int k = kk * 32 + q * 8 + j;
    int c = ct * 16 + n;
    float v = (c < C_) ? W[k * C_ + c] : 0.f;
    _Float16 h1 = (_Float16)v;
    union { _Float16 h; ushort u; } cv;
    cv.h = (plane == 0) ? h1 : (_Float16)(v - (float)h1);
    Wf[i] = cv.u;
}

// Block = 320 threads (5 waves) = 2 batch elements (160 rows). Wave w: rows
// [w*32, w*32+32) as two 16-row MFMA tiles, all 80 (padded) cols.
// A: global -> LDS (async, dbuf, XOR-swizzled chunks) -> f16-split frags.
// B: fragment-linear Wf, L2-resident.  C/D: col=lane&15, row=(lane>>4)*4+reg.
__global__ __launch_bounds__(320, 3) void gemm_ctc(
    const float* __restrict__ feat,   // [81920, 512] fp32
    const ushort* __restrict__ Wf,    // f16 split planes, fragment-linear
    const float* __restrict__ bias,   // [78] fp32
    float* __restrict__ probs,        // [81920, 78] fp32
    float* __restrict__ lab)          // [1024, 30] fp32
{
    __shared__ __align__(16) float Abuf[2][ROWS_PB * 32];  // 2 x 20 KB
    __shared__ int best_s[2][T_];

    const int tid  = threadIdx.x;
    const int w    = tid >> 6;
    const int lane = tid & 63;
    const int q    = lane >> 4;
    const int n    = lane & 15;

    f32x4 acc[2][5];
    #pragma unroll
    for (int t = 0; t < 2; ++t)
        #pragma unroll
        for (int ct = 0; ct < 5; ++ct)
            acc[t][ct] = (f32x4){0.f, 0.f, 0.f, 0.f};

    const float*  Abase = feat + (size_t)blockIdx.x * ROWS_PB * D_;
    const ushort* bp0   = Wf + lane * 8;

    // stage A slice kk (160 rows x 32 floats) into Abuf[buf], XOR-swizzled:
    // LDS chunk position (row, pc) holds global chunk (row, pc ^ (row&7)).
    auto stage = [&](int buf, int kk) {
        #pragma unroll
        for (int r = 0; r < 4; ++r) {
            int p   = r * 320 + w * 64 + lane;
            int row = p >> 3;
            int pc  = p & 7;
            int src = pc ^ (row & 7);
            const float* g = Abase + (size_t)row * D_ + kk * 32 + src * 4;
            float* l = &Abuf[buf][(size_t)(r * 320 + w * 64) * 4];  // wave-uniform
            load_lds16(g, l);
        }
    };

    stage(0, 0);
    int cur = 0;
    for (int kk = 0; kk < NKK; ++kk) {
        __syncthreads();                 // compiler drains vmcnt -> Abuf[cur] ready
        if (kk < NKK - 1) stage(cur ^ 1, kk + 1);

        const float* Ab = &Abuf[cur][0];
        f16x8 a1f[2], a2f[2];
        #pragma unroll
        for (int t = 0; t < 2; ++t) {
            int rowl = w * 32 + t * 16 + n;
            int sw   = n & 7;            // rowl & 7 == n & 7 (base multiple of 16)
            float4 f0 = *(const float4*)(Ab + rowl * 32 + (((2 * q)     ^ sw) * 4));
            float4 f1 = *(const float4*)(Ab + rowl * 32 + (((2 * q + 1) ^ sw) * 4));
            float v[8] = {f0.x, f0.y, f0.z, f0.w, f1.x, f1.y, f1.z, f1.w};
            #pragma unroll
            for (int j = 0; j < 8; ++j) {
                _Float16 h = (_Float16)v[j];
                a1f[t][j] = h;
                a2f[t][j] = (_Float16)(v[j] - (float)h);
            }
        }
        #pragma unroll
        for (int ct = 0; ct < 5; ++ct) {
            const ushort* bp = bp0 + (ct * NKK + kk) * FRAG;
            f16x8 b1 = *(const f16x8*)bp;
            f16x8 b2 = *(const f16x8*)(bp + PLANE_STRIDE);
            acc[0][ct] = __builtin_amdgcn_mfma_f32_16x16x32_f16(a1f[0], b1, acc[0][ct], 0, 0, 0);
            acc[0][ct] = __builtin_amdgcn_mfma_f32_16x16x32_f16(a2f[0], b1, acc[0][ct], 0, 0, 0);
            acc[0][ct] = __builtin_amdgcn_mfma_f32_16x16x32_f16(a1f[0], b2, acc[0][ct], 0, 0, 0);
            acc[0][ct] = __builtin_amdgcn_mfma_f32_16x16x32_f16(a2f[0], b2, acc[0][ct], 0, 0, 0);
            acc[1][ct] = __builtin_amdgcn_mfma_f32_16x16x32_f16(a1f[1], b1, acc[1][ct], 0, 0, 0);
            acc[1][ct] = __builtin_amdgcn_mfma_f32_16x16x32_f16(a2f[1], b1, acc[1][ct], 0, 0, 0);
            acc[1][ct] = __builtin_amdgcn_mfma_f32_16x16x32_f16(a1f[1], b2, acc[1][ct], 0, 0, 0);
            acc[1][ct] = __builtin_amdgcn_mfma_f32_16x16x32_f16(a2f[1], b2, acc[1][ct], 0, 0, 0);
        }
        cur ^= 1;
    }

    // ---- epilogue: bias + argmax + softmax + nontemporal stores ----
    #pragma unroll
    for (int t = 0; t < 2; ++t) {
        float x[5][4];
        #pragma unroll
        for (int ct = 0; ct < 5; ++ct) {
            int c = ct * 16 + n;
            bool valid = (c < C_);
            float bv = valid ? bias[c] : 0.f;
            #pragma unroll
            for (int r = 0; r < 4; ++r)
                x[ct][r] = valid ? (acc[t][ct][r] + bv) : -INFINITY;
        }
        float av[4]; int ai[4];
        #pragma unroll
        for (int r = 0; r < 4; ++r) {
            av[r] = x[0][r]; ai[r] = n;
            #pragma unroll
            for (int ct = 1; ct < 5; ++ct) {
                int c = ct * 16 + n;
                if (x[ct][r] > av[r]) { av[r] = x[ct][r]; ai[r] = c; }
            }
        }
        #pragma unroll
        for (int off = 8; off >= 1; off >>= 1) {
            #pragma unroll
            for (int r = 0; r < 4; ++r) {
                float ov = __shfl_xor(av[r], off, 16);
                int   oi = __shfl_xor(ai[r], off, 16);
                if (ov > av[r] || (ov == av[r] && oi < ai[r])) { av[r] = ov; ai[r] = oi; }
            }
        }
        float s[4] = {0.f, 0.f, 0.f, 0.f};
        #pragma unroll
        for (int ct = 0; ct < 5; ++ct)
            #pragma unroll
            for (int r = 0; r < 4; ++r) {
                x[ct][r] = __expf(x[ct][r] - av[r]);   // -INF -> 0
                s[r] += x[ct][r];
            }
        #pragma unroll
        for (int off = 8; off >= 1; off >>= 1)
            #pragma unroll
            for (int r = 0; r < 4; ++r) s[r] += __shfl_xor(s[r], off, 16);

        // wave w, tile t covers global rows blk*160 + w*32 + t*16 + (q*4 + r)
        const size_t growb = (size_t)blockIdx.x * ROWS_PB + w * 32 + t * 16 + q * 4;
        #pragma unroll
        for (int r = 0; r < 4; ++r) {
            float inv = 1.f / s[r];
            float* op = probs + (growb + r) * C_;
            #pragma unroll
            for (int ct = 0; ct < 5; ++ct) {
                int c = ct * 16 + n;
                if (c < C_) __builtin_nontemporal_store(x[ct][r] * inv, op + c);
            }
        }
        if (n == 0) {
            // local row index within the block's 160 rows -> (batch, time)
            int rl = w * 32 + t * 16 + q * 4;   // + r below
            #pragma unroll
            for (int r = 0; r < 4; ++r) {
                int rr = rl + r;
                best_s[rr / T_][rr % T_] = ai[r];
            }
        }
    }
    __syncthreads();

    // in-block CTC greedy decode (2 batch elements)
    if (tid < 2) {
        const int* bs = best_s[tid];
        float* op = lab + ((size_t)blockIdx.x * 2 + tid) * PRED_;
        int prev = -1, pos = 0;
        for (int t2 = 0; t2 < T_; ++t2) {
            int v = bs[t2];
            if (v != BLANK_ && v != prev) {
                if (pos < PRED_) op[pos] = (float)v;
                ++pos;
            }
            prev = v;
        }
        for (int i2 = (pos < PRED_ ? pos : PRED_); i2 < PRED_; ++i2) op[i2] = -1.f;
    }
}

extern "C" void kernel_launch(void* const* d_in, const int* in_sizes, int n_in,
                              void* d_out, int out_size, void* d_ws, size_t ws_size,
                              hipStream_t stream) {
    const float* feat = (const float*)d_in[0];   // fp32 [1024,80,512]
    const float* W    = (const float*)d_in[1];   // fp32 [512,78]
    const float* bias = (const float*)d_in[2];   // fp32 [78]
    // d_in[3]=y, d_in[4]=times : unused
    float*  probs = (float*)d_out;
    float*  lab   = probs + (size_t)B_ * T_ * C_;
    ushort* Wf    = (ushort*)d_ws;               // 163840 B scratch

    hipLaunchKernelGGL(prep_w, dim3(320), dim3(256), 0, stream, W, Wf);
    hipLaunchKernelGGL(gemm_ctc, dim3(B_ / 2), dim3(320), 0, stream,
                       feat, Wf, bias, probs, lab);
}